// Round 1
// baseline (417.164 us; speedup 1.0000x reference)
//
#include <hip/hip_runtime.h>
#include <hip/hip_bf16.h>

typedef float f32x4 __attribute__((ext_vector_type(4)));
typedef __bf16 bf16x8 __attribute__((ext_vector_type(8)));
typedef unsigned short ushort_t;
typedef ushort_t u16x8 __attribute__((ext_vector_type(8)));

// ---------------------------------------------------------------------------
// fp32 -> bf16 round-to-nearest-even (no NaN concern: inputs are finite)
// ---------------------------------------------------------------------------
__device__ inline ushort_t f2bf_rne(float f) {
  unsigned u = __builtin_bit_cast(unsigned, f);
  unsigned r = (u + 0x7fffu + ((u >> 16) & 1u)) >> 16;
  return (ushort_t)r;
}

// ---------------------------------------------------------------------------
// Kernel 1: 2:4 prune (exact fp32 argsort-stable semantics) + cast to bf16.
// Each thread handles 8 floats = 2 groups of 4. Writes one 16B bf16 chunk.
// ---------------------------------------------------------------------------
__global__ void prune_cast_kernel(const float* __restrict__ x,
                                  ushort_t* __restrict__ xsp, long n8) {
  long i = (long)blockIdx.x * blockDim.x + threadIdx.x;
  if (i >= n8) return;
  const float4* p = reinterpret_cast<const float4*>(x);
  float4 g0 = p[2 * i];
  float4 g1 = p[2 * i + 1];
  float v[8] = {g0.x, g0.y, g0.z, g0.w, g1.x, g1.y, g1.z, g1.w};
  u16x8 o;
#pragma unroll
  for (int g = 0; g < 2; ++g) {
    float a[4];
#pragma unroll
    for (int j = 0; j < 4; ++j) a[j] = fabsf(v[g * 4 + j]);
#pragma unroll
    for (int j = 0; j < 4; ++j) {
      int rank = 0;
#pragma unroll
      for (int k = 0; k < 4; ++k) {
        if (k == j) continue;
        // stable ascending sort rank: strictly-smaller, or equal-and-earlier
        rank += (a[k] < a[j]) || (a[k] == a[j] && k < j);
      }
      o[g * 4 + j] = (rank >= 2) ? f2bf_rne(v[g * 4 + j]) : (ushort_t)0;
    }
  }
  reinterpret_cast<u16x8*>(xsp)[i] = o;
}

// ---------------------------------------------------------------------------
// Kernel 2: fp32 -> bf16 cast of the weight matrix (8 elems / thread).
// ---------------------------------------------------------------------------
__global__ void cast_bf16_kernel(const float* __restrict__ w,
                                 ushort_t* __restrict__ wb, long n8) {
  long i = (long)blockIdx.x * blockDim.x + threadIdx.x;
  if (i >= n8) return;
  const float4* p = reinterpret_cast<const float4*>(w);
  float4 g0 = p[2 * i];
  float4 g1 = p[2 * i + 1];
  u16x8 o;
  o[0] = f2bf_rne(g0.x); o[1] = f2bf_rne(g0.y);
  o[2] = f2bf_rne(g0.z); o[3] = f2bf_rne(g0.w);
  o[4] = f2bf_rne(g1.x); o[5] = f2bf_rne(g1.y);
  o[6] = f2bf_rne(g1.z); o[7] = f2bf_rne(g1.w);
  reinterpret_cast<u16x8*>(wb)[i] = o;
}

// ---------------------------------------------------------------------------
// Kernel 3: bf16 GEMM, C[m][n] = sum_k A[m][k] * B[n][k]  (B^T layout)
// m97 structure: 128x128 tile, BK=64, 4 waves (2x2), 4x4 acc of 16x16x32
// fragments per wave, global_load_lds width-16 staging, linear LDS.
// ---------------------------------------------------------------------------
#define BM 128
#define BN 128
#define BK 64

__global__ __launch_bounds__(256) void gemm_bf16_kernel(
    const ushort_t* __restrict__ A,  // [M][K] bf16 (pruned x)
    const ushort_t* __restrict__ B,  // [N][K] bf16 (weight)
    float* __restrict__ C,           // [M][N] fp32
    int M, int N, int K) {
  __shared__ ushort_t As[BM * BK];  // row-major [128][64]
  __shared__ ushort_t Bs[BN * BK];

  const int tid = threadIdx.x;
  const int lane = tid & 63;
  const int wid = tid >> 6;
  const int bm = blockIdx.y;
  const int bn = blockIdx.x;
  const int wr = wid >> 1;  // wave row (0..1) -> 64-row slab
  const int wc = wid & 1;   // wave col (0..1) -> 64-col slab

  f32x4 acc[4][4];
#pragma unroll
  for (int i = 0; i < 4; ++i)
#pragma unroll
    for (int j = 0; j < 4; ++j) acc[i][j] = f32x4{0.f, 0.f, 0.f, 0.f};

  // staging geometry: each global_load_lds inst moves 64 lanes x 16B = 1024B
  // = 8 rows of the [.][64] bf16 tile. chunk c covers rows 8c..8c+7.
  // lane covers row 8c + lane/8, k-offset (lane%8)*8 (bf16 elems).
  const int s_row = lane >> 3;        // 0..7 within chunk
  const int s_kcol = (lane & 7) * 8;  // bf16 index within row

  const long a_row0 = (long)bm * BM;
  const long b_row0 = (long)bn * BN;

  // fragment read geometry (16x16x32 bf16):
  // A-frag lane l: row = l&15, k = (l>>4)*8 + j ; B-frag identical on [n][k].
  const int f_rc = lane & 15;
  const int f_k = (lane >> 4) * 8;

  for (int kt = 0; kt < K; kt += BK) {
    // ---- stage A tile (4 chunks per wave) ----
#pragma unroll
    for (int i = 0; i < 4; ++i) {
      const int c = wid * 4 + i;  // chunk 0..15
      const ushort_t* g = A + (a_row0 + c * 8 + s_row) * K + kt + s_kcol;
      __builtin_amdgcn_global_load_lds(
          (const __attribute__((address_space(1))) void*)g,
          (__attribute__((address_space(3))) void*)&As[c * 8 * BK + lane * 8],
          16, 0, 0);
    }
    // ---- stage B tile ----
#pragma unroll
    for (int i = 0; i < 4; ++i) {
      const int c = wid * 4 + i;
      const ushort_t* g = B + (b_row0 + c * 8 + s_row) * K + kt + s_kcol;
      __builtin_amdgcn_global_load_lds(
          (const __attribute__((address_space(1))) void*)g,
          (__attribute__((address_space(3))) void*)&Bs[c * 8 * BK + lane * 8],
          16, 0, 0);
    }
    __syncthreads();

    // ---- compute: 2 k-substeps x 16 MFMA ----
#pragma unroll
    for (int ks = 0; ks < 2; ++ks) {
      bf16x8 af[4], bfv[4];
#pragma unroll
      for (int mi = 0; mi < 4; ++mi) {
        const int row = wr * 64 + mi * 16 + f_rc;
        af[mi] = *reinterpret_cast<const bf16x8*>(&As[row * BK + ks * 32 + f_k]);
      }
#pragma unroll
      for (int ni = 0; ni < 4; ++ni) {
        const int row = wc * 64 + ni * 16 + f_rc;
        bfv[ni] = *reinterpret_cast<const bf16x8*>(&Bs[row * BK + ks * 32 + f_k]);
      }
#pragma unroll
      for (int mi = 0; mi < 4; ++mi)
#pragma unroll
        for (int ni = 0; ni < 4; ++ni)
          acc[mi][ni] = __builtin_amdgcn_mfma_f32_16x16x32_bf16(
              af[mi], bfv[ni], acc[mi][ni], 0, 0, 0);
    }
    __syncthreads();
  }

  // ---- epilogue: C/D layout col=lane&15, row=(lane>>4)*4+r ----
#pragma unroll
  for (int mi = 0; mi < 4; ++mi)
#pragma unroll
    for (int ni = 0; ni < 4; ++ni)
#pragma unroll
      for (int r = 0; r < 4; ++r) {
        const long row = a_row0 + wr * 64 + mi * 16 + (lane >> 4) * 4 + r;
        const long col = b_row0 + wc * 64 + ni * 16 + (lane & 15);
        C[row * N + col] = acc[mi][ni][r];
      }
}

// ---------------------------------------------------------------------------
// Launch
// ---------------------------------------------------------------------------
extern "C" void kernel_launch(void* const* d_in, const int* in_sizes, int n_in,
                              void* d_out, int out_size, void* d_ws,
                              size_t ws_size, hipStream_t stream) {
  const float* x = (const float*)d_in[0];
  const float* w = (const float*)d_in[1];
  float* out = (float*)d_out;

  const int K = 4096;
  const long M = (long)in_sizes[0] / K;  // 8192
  const int N = in_sizes[1] / K;         // 4096

  ushort_t* xsp = (ushort_t*)d_ws;             // [M][K] bf16: 67 MB
  ushort_t* wb = xsp + (long)M * K;            // [N][K] bf16: 33.5 MB

  const long n8x = M * K / 8;
  prune_cast_kernel<<<(int)((n8x + 255) / 256), 256, 0, stream>>>(x, xsp, n8x);

  const long n8w = (long)N * K / 8;
  cast_bf16_kernel<<<(int)((n8w + 255) / 256), 256, 0, stream>>>(w, wb, n8w);

  dim3 grid(N / BN, (int)(M / BM));
  gemm_bf16_kernel<<<grid, 256, 0, stream>>>(xsp, wb, out, (int)M, N, K);
}

// Round 2
// 357.010 us; speedup vs baseline: 1.1685x; 1.1685x over previous
//
#include <hip/hip_runtime.h>
#include <hip/hip_bf16.h>

typedef float f32x4 __attribute__((ext_vector_type(4)));
typedef __bf16 bf16x8 __attribute__((ext_vector_type(8)));
typedef unsigned short ushort_t;
typedef ushort_t u16x8 __attribute__((ext_vector_type(8)));

// ---------------------------------------------------------------------------
// fp32 -> bf16 round-to-nearest-even
// ---------------------------------------------------------------------------
__device__ inline ushort_t f2bf_rne(float f) {
  unsigned u = __builtin_bit_cast(unsigned, f);
  unsigned r = (u + 0x7fffu + ((u >> 16) & 1u)) >> 16;
  return (ushort_t)r;
}

// ---------------------------------------------------------------------------
// Kernel 1: 2:4 prune (exact fp32 argsort-stable semantics) + cast to bf16.
// ---------------------------------------------------------------------------
__global__ void prune_cast_kernel(const float* __restrict__ x,
                                  ushort_t* __restrict__ xsp, long n8) {
  long i = (long)blockIdx.x * blockDim.x + threadIdx.x;
  if (i >= n8) return;
  const float4* p = reinterpret_cast<const float4*>(x);
  float4 g0 = p[2 * i];
  float4 g1 = p[2 * i + 1];
  float v[8] = {g0.x, g0.y, g0.z, g0.w, g1.x, g1.y, g1.z, g1.w};
  u16x8 o;
#pragma unroll
  for (int g = 0; g < 2; ++g) {
    float a[4];
#pragma unroll
    for (int j = 0; j < 4; ++j) a[j] = fabsf(v[g * 4 + j]);
#pragma unroll
    for (int j = 0; j < 4; ++j) {
      int rank = 0;
#pragma unroll
      for (int k = 0; k < 4; ++k) {
        if (k == j) continue;
        rank += (a[k] < a[j]) || (a[k] == a[j] && k < j);
      }
      o[g * 4 + j] = (rank >= 2) ? f2bf_rne(v[g * 4 + j]) : (ushort_t)0;
    }
  }
  reinterpret_cast<u16x8*>(xsp)[i] = o;
}

// ---------------------------------------------------------------------------
// Kernel 2: fp32 -> bf16 cast of the weight matrix.
// ---------------------------------------------------------------------------
__global__ void cast_bf16_kernel(const float* __restrict__ w,
                                 ushort_t* __restrict__ wb, long n8) {
  long i = (long)blockIdx.x * blockDim.x + threadIdx.x;
  if (i >= n8) return;
  const float4* p = reinterpret_cast<const float4*>(w);
  float4 g0 = p[2 * i];
  float4 g1 = p[2 * i + 1];
  u16x8 o;
  o[0] = f2bf_rne(g0.x); o[1] = f2bf_rne(g0.y);
  o[2] = f2bf_rne(g0.z); o[3] = f2bf_rne(g0.w);
  o[4] = f2bf_rne(g1.x); o[5] = f2bf_rne(g1.y);
  o[6] = f2bf_rne(g1.z); o[7] = f2bf_rne(g1.w);
  reinterpret_cast<u16x8*>(wb)[i] = o;
}

// ---------------------------------------------------------------------------
// Kernel 3: 256x256 8-phase bf16 GEMM (m201 template, plain HIP).
// C[m][n] = sum_k A[m][k]*B[n][k].  8 waves (2Mx4N), BK=64, 128 KiB LDS
// (2 dbuf x 2 half x 128x64 x {A,B}).  Counted vmcnt, raw barriers, setprio,
// XOR swizzle (row bits 2-3 -> byte bits 4-5) on both stage-source and read.
// ---------------------------------------------------------------------------
#define BAR() __builtin_amdgcn_s_barrier()
#define WAIT_LGKM0() asm volatile("s_waitcnt lgkmcnt(0)" ::: "memory")
#define WAIT_VM4() asm volatile("s_waitcnt vmcnt(4)" ::: "memory")

#define STAGE_A(t1, h, par)                                                    \
  {                                                                            \
    const ushort_t* g0 =                                                       \
        A + (a_row0 + (h) * 128 + srow) * (long)Kd + (t1) * 64 + scol0;        \
    const ushort_t* g1 =                                                       \
        A + (a_row0 + (h) * 128 + srow + 8) * (long)Kd + (t1) * 64 + scol1;    \
    ushort_t* l0 = &ldsA[((par) * 2 + (h)) * 8192 + w * 1024];                 \
    __builtin_amdgcn_global_load_lds(                                          \
        (const __attribute__((address_space(1))) void*)g0,                     \
        (__attribute__((address_space(3))) void*)l0, 16, 0, 0);                \
    __builtin_amdgcn_global_load_lds(                                          \
        (const __attribute__((address_space(1))) void*)g1,                     \
        (__attribute__((address_space(3))) void*)(l0 + 512), 16, 0, 0);        \
  }

#define STAGE_B(t1, h, par)                                                    \
  {                                                                            \
    const ushort_t* g0 =                                                       \
        B + (b_row0 + (h) * 128 + srow) * (long)Kd + (t1) * 64 + scol0;        \
    const ushort_t* g1 =                                                       \
        B + (b_row0 + (h) * 128 + srow + 8) * (long)Kd + (t1) * 64 + scol1;    \
    ushort_t* l0 = &ldsB[((par) * 2 + (h)) * 8192 + w * 1024];                 \
    __builtin_amdgcn_global_load_lds(                                          \
        (const __attribute__((address_space(1))) void*)g0,                     \
        (__attribute__((address_space(3))) void*)l0, 16, 0, 0);                \
    __builtin_amdgcn_global_load_lds(                                          \
        (const __attribute__((address_space(1))) void*)g1,                     \
        (__attribute__((address_space(3))) void*)(l0 + 512), 16, 0, 0);        \
  }

#define LDA_FRAG(dst, par, mi, s)                                              \
  dst = *reinterpret_cast<const bf16x8*>(                                      \
      reinterpret_cast<const char*>(ldsA) + ((par) * 2 + wr) * 16384 +         \
      (mi) * 2048 + (s) * 64 + roff);

#define LDB_FRAG(dst, par, ni, s)                                              \
  dst = *reinterpret_cast<const bf16x8*>(                                      \
      reinterpret_cast<const char*>(ldsB) + ((par) * 2 + (wc >> 1)) * 16384 +  \
      (wc & 1) * 8192 + (ni) * 2048 + (s) * 64 + roff);

#define MFMA_Q(MH, NH)                                                         \
  __builtin_amdgcn_s_setprio(1);                                               \
  _Pragma("unroll") for (int s = 0; s < 2; ++s)                                \
  _Pragma("unroll") for (int mi = 0; mi < 4; ++mi)                             \
  _Pragma("unroll") for (int ni = 0; ni < 2; ++ni)                             \
      acc[(MH) * 4 + mi][(NH) * 2 + ni] =                                      \
          __builtin_amdgcn_mfma_f32_16x16x32_bf16(                             \
              af[mi][s], bfr[(NH) * 2 + ni][s],                                \
              acc[(MH) * 4 + mi][(NH) * 2 + ni], 0, 0, 0);                     \
  __builtin_amdgcn_s_setprio(0);

#define KTILE(t, PAR)                                                          \
  { /* phase 0: read A-mh0 + B n0..1 ; stage A0(t+1) ; MFMA Q(0,0) */          \
    _Pragma("unroll") for (int mi = 0; mi < 4; ++mi)                           \
    _Pragma("unroll") for (int s = 0; s < 2; ++s)                              \
        LDA_FRAG(af[mi][s], PAR, mi, s)                                        \
    _Pragma("unroll") for (int ni = 0; ni < 2; ++ni)                           \
    _Pragma("unroll") for (int s = 0; s < 2; ++s)                              \
        LDB_FRAG(bfr[ni][s], PAR, ni, s)                                       \
    if ((t) + 1 < NT) STAGE_A((t) + 1, 0, (PAR) ^ 1)                           \
    BAR();                                                                     \
    WAIT_LGKM0();                                                              \
    MFMA_Q(0, 0)                                                               \
    BAR();                                                                     \
    /* phase 1: read B n2..3 ; stage A1(t+1) ; MFMA Q(0,1) */                  \
    _Pragma("unroll") for (int ni = 2; ni < 4; ++ni)                           \
    _Pragma("unroll") for (int s = 0; s < 2; ++s)                              \
        LDB_FRAG(bfr[ni][s], PAR, ni, s)                                       \
    if ((t) + 1 < NT) STAGE_A((t) + 1, 1, (PAR) ^ 1)                           \
    BAR();                                                                     \
    WAIT_LGKM0();                                                              \
    MFMA_Q(0, 1)                                                               \
    BAR();                                                                     \
    /* phase 2: read A-mh1 ; stage B0(t+2) ; MFMA Q(1,1) */                    \
    _Pragma("unroll") for (int mi = 0; mi < 4; ++mi)                           \
    _Pragma("unroll") for (int s = 0; s < 2; ++s)                              \
        LDA_FRAG(af[mi][s], PAR, 4 + mi, s)                                    \
    if ((t) + 2 < NT) STAGE_B((t) + 2, 0, PAR)                                 \
    BAR();                                                                     \
    WAIT_LGKM0();                                                              \
    MFMA_Q(1, 1)                                                               \
    BAR();                                                                     \
    /* phase 3: stage B1(t+2) ; MFMA Q(1,0) ; boundary vmcnt(4) */             \
    if ((t) + 2 < NT) STAGE_B((t) + 2, 1, PAR)                                 \
    BAR();                                                                     \
    MFMA_Q(1, 0)                                                               \
    WAIT_VM4();                                                                \
    BAR();                                                                     \
  }

__global__ __launch_bounds__(512, 1) void gemm256_kernel(
    const ushort_t* __restrict__ A,  // [M][K] bf16 (pruned x)
    const ushort_t* __restrict__ B,  // [N][K] bf16 (weight)
    float* __restrict__ C,           // [M][N] fp32
    int M, int N, int Kd) {
  __shared__ ushort_t ldsA[4 * 8192];  // 4 slots x 16 KiB (par,half)
  __shared__ ushort_t ldsB[4 * 8192];

  const int tid = threadIdx.x;
  const int lane = tid & 63;
  const int w = tid >> 6;   // wave 0..7
  const int wr = w >> 2;    // 0..1 -> 128-row half
  const int wc = w & 3;     // 0..3 -> 64-col slab

  // XCD-bijective grid swizzle (gridDim.x % 8 == 0)
  const int b = blockIdx.x;
  const int wg = (b & 7) * (gridDim.x >> 3) + (b >> 3);
  const int nbn = N / 256;
  const int bm = wg / nbn, bn = wg % nbn;
  const long a_row0 = (long)bm * 256;
  const long b_row0 = (long)bn * 256;
  const int NT = Kd / 64;

  // staging geometry: lane covers row w*16 + i*8 + (l>>3),
  // source col pre-swizzled (inverse of read swizzle): bits from (l>>5, i)
  const int srow = w * 16 + (lane >> 3);
  const int scol0 = ((lane & 7) * 8) ^ ((lane >> 5) << 3);
  const int scol1 = scol0 ^ 16;

  // fragment read geometry: logical byte r*128 + (l>>4)*16 (+ s*64 + mi*2048),
  // physical = logical ^ ((r bits 2..3) << 4)
  const int rl = lane & 15;
  const int roff = (rl * 128 + ((lane >> 4) << 4)) ^ (((rl >> 2) & 3) << 4);

  f32x4 acc[8][4];
#pragma unroll
  for (int i = 0; i < 8; ++i)
#pragma unroll
    for (int j = 0; j < 4; ++j) acc[i][j] = f32x4{0.f, 0.f, 0.f, 0.f};

  bf16x8 af[4][2];   // current m-half A fragments
  bf16x8 bfr[4][2];  // all 4 n fragments (both halves kept live)

  // ---- prologue: stage K0 fully + B halves of K1; allow 2 half-tiles in
  // flight (vmcnt(4)) ----
  STAGE_B(0, 0, 0)
  STAGE_B(0, 1, 0)
  STAGE_A(0, 0, 0)
  STAGE_A(0, 1, 0)
  STAGE_B(1, 0, 1)
  STAGE_B(1, 1, 1)
  WAIT_VM4();
  BAR();

  for (int t = 0; t < NT; t += 2) {
    KTILE(t, 0)
    KTILE(t + 1, 1)
  }

  // ---- epilogue: C/D layout col=lane&15, row=(lane>>4)*4+r ----
  const int orow = (lane >> 4) * 4;
  const int ocol = lane & 15;
#pragma unroll
  for (int mi = 0; mi < 8; ++mi)
#pragma unroll
    for (int ni = 0; ni < 4; ++ni) {
      const long r0 = a_row0 + wr * 128 + mi * 16 + orow;
      const long c0 = b_row0 + wc * 64 + ni * 16 + ocol;
#pragma unroll
      for (int r = 0; r < 4; ++r) C[(r0 + r) * N + c0] = acc[mi][ni][r];
    }
}

// ---------------------------------------------------------------------------
// Launch
// ---------------------------------------------------------------------------
extern "C" void kernel_launch(void* const* d_in, const int* in_sizes, int n_in,
                              void* d_out, int out_size, void* d_ws,
                              size_t ws_size, hipStream_t stream) {
  const float* x = (const float*)d_in[0];
  const float* w = (const float*)d_in[1];
  float* out = (float*)d_out;

  const int K = 4096;
  const long M = (long)in_sizes[0] / K;  // 8192
  const int N = in_sizes[1] / K;         // 4096

  ushort_t* xsp = (ushort_t*)d_ws;      // [M][K] bf16
  ushort_t* wb = xsp + (long)M * K;     // [N][K] bf16

  const long n8x = M * K / 8;
  prune_cast_kernel<<<(int)((n8x + 255) / 256), 256, 0, stream>>>(x, xsp, n8x);

  const long n8w = (long)N * K / 8;
  cast_bf16_kernel<<<(int)((n8w + 255) / 256), 256, 0, stream>>>(w, wb, n8w);

  const int nwg = (int)(M / 256) * (N / 256);  // 512, divisible by 8
  gemm256_kernel<<<nwg, 512, 0, stream>>>(xsp, wb, out, (int)M, N, K);
}

// Round 3
// 283.440 us; speedup vs baseline: 1.4718x; 1.2596x over previous
//
#include <hip/hip_runtime.h>
#include <hip/hip_bf16.h>

typedef float f32x4 __attribute__((ext_vector_type(4)));
typedef __bf16 bf16x8 __attribute__((ext_vector_type(8)));
typedef unsigned short ushort_t;
typedef ushort_t u16x8 __attribute__((ext_vector_type(8)));

// ---------------------------------------------------------------------------
// fp32 -> bf16 round-to-nearest-even
// ---------------------------------------------------------------------------
__device__ inline ushort_t f2bf_rne(float f) {
  unsigned u = __builtin_bit_cast(unsigned, f);
  unsigned r = (u + 0x7fffu + ((u >> 16) & 1u)) >> 16;
  return (ushort_t)r;
}

// ---------------------------------------------------------------------------
// Kernel 1: 2:4 prune (exact fp32 argsort-stable semantics) + cast to bf16.
// ---------------------------------------------------------------------------
__global__ void prune_cast_kernel(const float* __restrict__ x,
                                  ushort_t* __restrict__ xsp, long n8) {
  long i = (long)blockIdx.x * blockDim.x + threadIdx.x;
  if (i >= n8) return;
  const float4* p = reinterpret_cast<const float4*>(x);
  float4 g0 = p[2 * i];
  float4 g1 = p[2 * i + 1];
  float v[8] = {g0.x, g0.y, g0.z, g0.w, g1.x, g1.y, g1.z, g1.w};
  u16x8 o;
#pragma unroll
  for (int g = 0; g < 2; ++g) {
    float a[4];
#pragma unroll
    for (int j = 0; j < 4; ++j) a[j] = fabsf(v[g * 4 + j]);
#pragma unroll
    for (int j = 0; j < 4; ++j) {
      int rank = 0;
#pragma unroll
      for (int k = 0; k < 4; ++k) {
        if (k == j) continue;
        rank += (a[k] < a[j]) || (a[k] == a[j] && k < j);
      }
      o[g * 4 + j] = (rank >= 2) ? f2bf_rne(v[g * 4 + j]) : (ushort_t)0;
    }
  }
  reinterpret_cast<u16x8*>(xsp)[i] = o;
}

// ---------------------------------------------------------------------------
// Kernel 2: fp32 -> bf16 cast of the weight matrix.
// ---------------------------------------------------------------------------
__global__ void cast_bf16_kernel(const float* __restrict__ w,
                                 ushort_t* __restrict__ wb, long n8) {
  long i = (long)blockIdx.x * blockDim.x + threadIdx.x;
  if (i >= n8) return;
  const float4* p = reinterpret_cast<const float4*>(w);
  float4 g0 = p[2 * i];
  float4 g1 = p[2 * i + 1];
  u16x8 o;
  o[0] = f2bf_rne(g0.x); o[1] = f2bf_rne(g0.y);
  o[2] = f2bf_rne(g0.z); o[3] = f2bf_rne(g0.w);
  o[4] = f2bf_rne(g1.x); o[5] = f2bf_rne(g1.y);
  o[6] = f2bf_rne(g1.z); o[7] = f2bf_rne(g1.w);
  reinterpret_cast<u16x8*>(wb)[i] = o;
}

// ---------------------------------------------------------------------------
// Kernel 3: 256x256 8-phase bf16 GEMM.  C[m][n] = sum_k A[m][k]*B[n][k].
// 8 waves (2Mx4N), BK=64, 128 KiB LDS double-buffered.  Counted vmcnt, raw
// barriers, setprio.  Full 3-bit XOR swizzle: physical 16B-chunk =
// logical_chunk ^ (row&7)  (byte bits 4-6 XOR row bits 0-2), applied to the
// global stage SOURCE (linear global_load_lds dest) and to the ds_read addr.
// ---------------------------------------------------------------------------
#define BAR() __builtin_amdgcn_s_barrier()
#define WAIT_LGKM0() asm volatile("s_waitcnt lgkmcnt(0)" ::: "memory")
#define WAIT_VM4() asm volatile("s_waitcnt vmcnt(4)" ::: "memory")

#define STAGE_A(t1, h, par)                                                    \
  {                                                                            \
    const ushort_t* g0 =                                                       \
        A + (a_row0 + (h) * 128 + srow) * (long)Kd + (t1) * 64 + scol;         \
    const ushort_t* g1 =                                                       \
        A + (a_row0 + (h) * 128 + srow + 8) * (long)Kd + (t1) * 64 + scol;     \
    ushort_t* l0 = &ldsA[((par) * 2 + (h)) * 8192 + w * 1024];                 \
    __builtin_amdgcn_global_load_lds(                                          \
        (const __attribute__((address_space(1))) void*)g0,                     \
        (__attribute__((address_space(3))) void*)l0, 16, 0, 0);                \
    __builtin_amdgcn_global_load_lds(                                          \
        (const __attribute__((address_space(1))) void*)g1,                     \
        (__attribute__((address_space(3))) void*)(l0 + 512), 16, 0, 0);        \
  }

#define STAGE_B(t1, h, par)                                                    \
  {                                                                            \
    const ushort_t* g0 =                                                       \
        B + (b_row0 + (h) * 128 + srow) * (long)Kd + (t1) * 64 + scol;         \
    const ushort_t* g1 =                                                       \
        B + (b_row0 + (h) * 128 + srow + 8) * (long)Kd + (t1) * 64 + scol;     \
    ushort_t* l0 = &ldsB[((par) * 2 + (h)) * 8192 + w * 1024];                 \
    __builtin_amdgcn_global_load_lds(                                          \
        (const __attribute__((address_space(1))) void*)g0,                     \
        (__attribute__((address_space(3))) void*)l0, 16, 0, 0);                \
    __builtin_amdgcn_global_load_lds(                                          \
        (const __attribute__((address_space(1))) void*)g1,                     \
        (__attribute__((address_space(3))) void*)(l0 + 512), 16, 0, 0);        \
  }

#define LDA_FRAG(dst, par, mi, s)                                              \
  dst = *reinterpret_cast<const bf16x8*>(                                      \
      reinterpret_cast<const char*>(ldsA) + ((par) * 2 + wr) * 16384 +         \
      (mi) * 2048 + ((s) ? roff1 : roff0));

#define LDB_FRAG(dst, par, ni, s)                                              \
  dst = *reinterpret_cast<const bf16x8*>(                                      \
      reinterpret_cast<const char*>(ldsB) + ((par) * 2 + (wc >> 1)) * 16384 +  \
      (wc & 1) * 8192 + (ni) * 2048 + ((s) ? roff1 : roff0));

#define MFMA_Q(MH, NH)                                                         \
  __builtin_amdgcn_s_setprio(1);                                               \
  _Pragma("unroll") for (int s = 0; s < 2; ++s)                                \
  _Pragma("unroll") for (int mi = 0; mi < 4; ++mi)                             \
  _Pragma("unroll") for (int ni = 0; ni < 2; ++ni)                             \
      acc[(MH) * 4 + mi][(NH) * 2 + ni] =                                      \
          __builtin_amdgcn_mfma_f32_16x16x32_bf16(                             \
              af[mi][s], bfr[(NH) * 2 + ni][s],                                \
              acc[(MH) * 4 + mi][(NH) * 2 + ni], 0, 0, 0);                     \
  __builtin_amdgcn_s_setprio(0);

#define KTILE(t, PAR)                                                          \
  { /* phase 0: read A-mh0 + B n0..1 ; stage A0(t+1) ; MFMA Q(0,0) */          \
    _Pragma("unroll") for (int mi = 0; mi < 4; ++mi)                           \
    _Pragma("unroll") for (int s = 0; s < 2; ++s)                              \
        LDA_FRAG(af[mi][s], PAR, mi, s)                                        \
    _Pragma("unroll") for (int ni = 0; ni < 2; ++ni)                           \
    _Pragma("unroll") for (int s = 0; s < 2; ++s)                              \
        LDB_FRAG(bfr[ni][s], PAR, ni, s)                                       \
    if ((t) + 1 < NT) STAGE_A((t) + 1, 0, (PAR) ^ 1)                           \
    BAR();                                                                     \
    WAIT_LGKM0();                                                              \
    MFMA_Q(0, 0)                                                               \
    BAR();                                                                     \
    /* phase 1: read B n2..3 ; stage A1(t+1) ; MFMA Q(0,1) */                  \
    _Pragma("unroll") for (int ni = 2; ni < 4; ++ni)                           \
    _Pragma("unroll") for (int s = 0; s < 2; ++s)                              \
        LDB_FRAG(bfr[ni][s], PAR, ni, s)                                       \
    if ((t) + 1 < NT) STAGE_A((t) + 1, 1, (PAR) ^ 1)                           \
    BAR();                                                                     \
    WAIT_LGKM0();                                                              \
    MFMA_Q(0, 1)                                                               \
    BAR();                                                                     \
    /* phase 2: read A-mh1 ; stage B0(t+2) ; MFMA Q(1,1) */                    \
    _Pragma("unroll") for (int mi = 0; mi < 4; ++mi)                           \
    _Pragma("unroll") for (int s = 0; s < 2; ++s)                              \
        LDA_FRAG(af[mi][s], PAR, 4 + mi, s)                                    \
    if ((t) + 2 < NT) STAGE_B((t) + 2, 0, PAR)                                 \
    BAR();                                                                     \
    WAIT_LGKM0();                                                              \
    MFMA_Q(1, 1)                                                               \
    BAR();                                                                     \
    /* phase 3: stage B1(t+2) ; MFMA Q(1,0) ; boundary vmcnt(4) */             \
    if ((t) + 2 < NT) STAGE_B((t) + 2, 1, PAR)                                 \
    BAR();                                                                     \
    MFMA_Q(1, 0)                                                               \
    WAIT_VM4();                                                                \
    BAR();                                                                     \
  }

__global__ __launch_bounds__(512, 1) void gemm256_kernel(
    const ushort_t* __restrict__ A,  // [M][K] bf16 (pruned x)
    const ushort_t* __restrict__ B,  // [N][K] bf16 (weight)
    float* __restrict__ C,           // [M][N] fp32
    int M, int N, int Kd) {
  __shared__ ushort_t ldsA[4 * 8192];  // 4 slots x 16 KiB (par,half)
  __shared__ ushort_t ldsB[4 * 8192];

  const int tid = threadIdx.x;
  const int lane = tid & 63;
  const int w = tid >> 6;   // wave 0..7
  const int wr = w >> 2;    // 0..1 -> 128-row half
  const int wc = w & 3;     // 0..3 -> 64-col slab

  // XCD-bijective grid swizzle (gridDim.x % 8 == 0)
  const int b = blockIdx.x;
  const int wg = (b & 7) * (gridDim.x >> 3) + (b >> 3);
  const int nbn = N / 256;
  const int bm = wg / nbn, bn = wg % nbn;
  const long a_row0 = (long)bm * 256;
  const long b_row0 = (long)bn * 256;
  const int NT = Kd / 64;

  // staging geometry: instr i of wave w, lane l writes LINEAR physical bytes
  // (row 16w+8i+(l>>3), chunk l&7).  Swizzle physical(r,c) <- logical(r,
  // c^(r&7)) so the global SOURCE chunk is (l&7) ^ ((l>>3)&7)  (same for
  // both instrs since (8+x)&7 == x&7).
  const int srow = w * 16 + (lane >> 3);
  const int scol = (((lane & 7) ^ ((lane >> 3) & 7)) << 3);  // ushort units

  // fragment read: logical (row = subtile + rl, chunk = q | s<<2) lives at
  // physical chunk (q | s<<2) ^ (rl&7).  s touches chunk bit 2 so it must be
  // folded INSIDE the XOR -> two precomputed offsets.
  const int rl = lane & 15;
  const int q = lane >> 4;
  const int roff0 = rl * 128 + (((q) ^ (rl & 7)) << 4);
  const int roff1 = rl * 128 + (((q | 4) ^ (rl & 7)) << 4);

  f32x4 acc[8][4];
#pragma unroll
  for (int i = 0; i < 8; ++i)
#pragma unroll
    for (int j = 0; j < 4; ++j) acc[i][j] = f32x4{0.f, 0.f, 0.f, 0.f};

  bf16x8 af[4][2];   // current m-half A fragments
  bf16x8 bfr[4][2];  // all 4 n fragments (both halves kept live)

  // ---- prologue: stage K0 fully + B halves of K1; vmcnt(4) lets the K1-B
  // loads stay in flight ----
  STAGE_B(0, 0, 0)
  STAGE_B(0, 1, 0)
  STAGE_A(0, 0, 0)
  STAGE_A(0, 1, 0)
  STAGE_B(1, 0, 1)
  STAGE_B(1, 1, 1)
  WAIT_VM4();
  BAR();

  for (int t = 0; t < NT; t += 2) {
    KTILE(t, 0)
    KTILE(t + 1, 1)
  }

  // ---- epilogue: C/D layout col=lane&15, row=(lane>>4)*4+r ----
  const int orow = (lane >> 4) * 4;
  const int ocol = lane & 15;
#pragma unroll
  for (int mi = 0; mi < 8; ++mi)
#pragma unroll
    for (int ni = 0; ni < 4; ++ni) {
      const long r0 = a_row0 + wr * 128 + mi * 16 + orow;
      const long c0 = b_row0 + wc * 64 + ni * 16 + ocol;
#pragma unroll
      for (int r = 0; r < 4; ++r) C[(r0 + r) * N + c0] = acc[mi][ni][r];
    }
}

// ---------------------------------------------------------------------------
// Launch
// ---------------------------------------------------------------------------
extern "C" void kernel_launch(void* const* d_in, const int* in_sizes, int n_in,
                              void* d_out, int out_size, void* d_ws,
                              size_t ws_size, hipStream_t stream) {
  const float* x = (const float*)d_in[0];
  const float* w = (const float*)d_in[1];
  float* out = (float*)d_out;

  const int K = 4096;
  const long M = (long)in_sizes[0] / K;  // 8192
  const int N = in_sizes[1] / K;         // 4096

  ushort_t* xsp = (ushort_t*)d_ws;      // [M][K] bf16
  ushort_t* wb = xsp + (long)M * K;     // [N][K] bf16

  const long n8x = M * K / 8;
  prune_cast_kernel<<<(int)((n8x + 255) / 256), 256, 0, stream>>>(x, xsp, n8x);

  const long n8w = (long)N * K / 8;
  cast_bf16_kernel<<<(int)((n8w + 255) / 256), 256, 0, stream>>>(w, wb, n8w);

  const int nwg = (int)(M / 256) * (N / 256);  // 512, divisible by 8
  gemm256_kernel<<<nwg, 512, 0, stream>>>(xsp, wb, out, (int)M, N, K);
}